// Round 1
// baseline (467.192 us; speedup 1.0000x reference)
//
#include <hip/hip_runtime.h>
#include <cstdint>
#include <cstddef>

// ---------- types ----------
typedef __bf16 bf16x8 __attribute__((ext_vector_type(8)));
typedef float f32x4 __attribute__((ext_vector_type(4)));
typedef unsigned short u16x8 __attribute__((ext_vector_type(8)));

__device__ static inline unsigned short f32_to_bf16_rne(float f) {
  unsigned int u = __float_as_uint(f);
  unsigned int r = 0x7FFFu + ((u >> 16) & 1u);
  return (unsigned short)((u + r) >> 16);
}

__device__ static inline void async16(const void* g, void* l) {
  __builtin_amdgcn_global_load_lds(
      (const __attribute__((address_space(1))) void*)g,
      (__attribute__((address_space(3))) void*)l,
      16, 0, 0);
}

// ---------- prep: Ucol[i] = U[i][1024] (contiguous fp32) ----------
__global__ __launch_bounds__(256) void prep_Ucol(const float* __restrict__ U,
                                                 float* __restrict__ Ucol) {
  const int i = blockIdx.x * 256 + threadIdx.x;
  Ucol[i] = U[(size_t)i * 1025 + 1024];
}

// ---------- prep: U_t[j][i] = bf16(U[i][j]), LDS-tiled transpose ----------
__global__ __launch_bounds__(256) void prep_U(const float* __restrict__ U,
                                              unsigned short* __restrict__ Ut) {
  __shared__ float tile[32][33];
  const int i0 = blockIdx.y * 32, j0 = blockIdx.x * 32;
  const int tx = threadIdx.x & 31, ty = threadIdx.x >> 5;  // 32 x 8
#pragma unroll
  for (int r = 0; r < 32; r += 8)
    tile[ty + r][tx] = U[(size_t)(i0 + ty + r) * 1025 + j0 + tx];
  __syncthreads();
#pragma unroll
  for (int r = 0; r < 32; r += 8)
    Ut[(size_t)(j0 + ty + r) * 1024 + i0 + tx] =
        f32_to_bf16_rne(tile[tx][ty + r]);
}

// ---------- prep: cast D,H rows to bf16; c[r], t[r] biases ----------
// Wave-per-row, grid-stride. No __syncthreads, no LDS.
// Each lane: 16 floats of D + 16 of H (4x float4 each), two 16B bf16 stores
// per matrix; per-lane slices of Ucol/W_h/W_d live in registers across rows.
__global__ __launch_bounds__(256) void prep_rows(
    const float* __restrict__ D, const float* __restrict__ H,
    const float* __restrict__ Ucol, const float* __restrict__ W,
    unsigned short* __restrict__ Db, unsigned short* __restrict__ Hb,
    float* __restrict__ cvec, float* __restrict__ tvec) {
  const int lane = threadIdx.x & 63;
  const int wv = threadIdx.x >> 6;
  const int col = lane * 16;

  float4 uc[4], wh[4], wd[4];
#pragma unroll
  for (int q = 0; q < 4; ++q) {
    uc[q] = *(const float4*)(Ucol + col + q * 4);
    wh[q] = *(const float4*)(W + col + q * 4);
    wd[q] = *(const float4*)(W + 1025 + col + q * 4);
  }
  const float wbias = W[1024];

  const int stride = gridDim.x * 4;
  for (int r = blockIdx.x * 4 + wv; r < 32768; r += stride) {
    const size_t base = (size_t)r * 1024 + col;
    float4 d4[4], h4[4];
#pragma unroll
    for (int q = 0; q < 4; ++q) d4[q] = *(const float4*)(D + base + q * 4);
#pragma unroll
    for (int q = 0; q < 4; ++q) h4[q] = *(const float4*)(H + base + q * 4);

    u16x8 db[2], hb[2];
#pragma unroll
    for (int q = 0; q < 4; ++q) {
      const float* dp = (const float*)&d4[q];
      const float* hp = (const float*)&h4[q];
#pragma unroll
      for (int e = 0; e < 4; ++e) {
        db[q >> 1][(q & 1) * 4 + e] = f32_to_bf16_rne(dp[e]);
        hb[q >> 1][(q & 1) * 4 + e] = f32_to_bf16_rne(hp[e]);
      }
    }
    *(u16x8*)(Db + base) = db[0];
    *(u16x8*)(Db + base + 8) = db[1];
    *(u16x8*)(Hb + base) = hb[0];
    *(u16x8*)(Hb + base + 8) = hb[1];

    float cp = 0.0f, tp = 0.0f;
#pragma unroll
    for (int q = 0; q < 4; ++q) {
      cp += d4[q].x * uc[q].x + d4[q].y * uc[q].y + d4[q].z * uc[q].z +
            d4[q].w * uc[q].w;
      cp += h4[q].x * wh[q].x + h4[q].y * wh[q].y + h4[q].z * wh[q].z +
            h4[q].w * wh[q].w;
      tp += d4[q].x * wd[q].x + d4[q].y * wd[q].y + d4[q].z * wd[q].z +
            d4[q].w * wd[q].w;
    }
#pragma unroll
    for (int off = 32; off > 0; off >>= 1) {
      cp += __shfl_down(cp, off);
      tp += __shfl_down(tp, off);
    }
    if (lane == 0) {
      cvec[r] = cp + wbias;
      tvec[r] = tp;
    }
  }
}

// ---------- MFMA GEMM: C[m][n] = sum_k A[m][k] * Bt[n][k] ----------
// XOR-swizzled LDS: slot chunk ch of row holds global chunk ch^(row&7).
// Staging permutes per-lane global sources (LDS dest stays lane-contiguous,
// satisfying global_load_lds's wave-uniform-base + lane*16 constraint).
template <bool FUSED>
__global__ __launch_bounds__(256) void gemm_bt(
    const unsigned short* __restrict__ A, const unsigned short* __restrict__ Bt,
    void* __restrict__ Cv, const float* __restrict__ rowBias,
    const float* __restrict__ colBias, int M, int N, int K,
    long sA, long sB, long sC) {
  __shared__ unsigned short As[128 * 64];
  __shared__ unsigned short Bs[128 * 64];

  const int tid = threadIdx.x;
  const int lane = tid & 63;
  const int wave = tid >> 6;
  const int wm = wave >> 1, wn = wave & 1;
  const int bz = blockIdx.z;
  const int m0 = blockIdx.y * 128;
  const int n0 = blockIdx.x * 128;

  const unsigned short* Ab = A + (size_t)bz * (size_t)sA;
  const unsigned short* Bb = Bt + (size_t)bz * (size_t)sB;

  size_t aOff[4], bOff[4];
  int ldsOff[4];
#pragma unroll
  for (int q = 0; q < 4; ++q) {
    int e = (q * 256 + tid) * 8;   // bf16 element index in 128x64 tile
    int row = e >> 6;              // tile-local row 0..127
    int ch = (e >> 3) & 7;         // chunk-of-8 within row
    int chSw = ch ^ (row & 7);     // swizzled source chunk
    ldsOff[q] = e;
    aOff[q] = (size_t)(m0 + row) * K + chSw * 8;
    bOff[q] = (size_t)(n0 + row) * K + chSw * 8;
  }

  const f32x4 zero = {0.0f, 0.0f, 0.0f, 0.0f};
  f32x4 acc[4][4];
#pragma unroll
  for (int i = 0; i < 4; ++i)
#pragma unroll
    for (int j = 0; j < 4; ++j) acc[i][j] = zero;

  const int rr = lane & 15;
  const int qd = lane >> 4;
  const int c0 = qd ^ (rr & 7);            // swizzled base chunk
  const int aRow = (wm * 64 + rr) * 64;
  const int bRow = (wn * 64 + rr) * 64;

  for (int k0 = 0; k0 < K; k0 += 64) {
#pragma unroll
    for (int q = 0; q < 4; ++q) async16(Ab + aOff[q] + k0, &As[ldsOff[q]]);
#pragma unroll
    for (int q = 0; q < 4; ++q) async16(Bb + bOff[q] + k0, &Bs[ldsOff[q]]);
    __syncthreads();

#pragma unroll
    for (int kk = 0; kk < 64; kk += 32) {
      const int co = (c0 ^ (kk >> 3)) * 8;  // kk=0 -> c0, kk=32 -> c0^4
      bf16x8 af[4], bfr[4];
#pragma unroll
      for (int mt = 0; mt < 4; ++mt)
        af[mt] = *(const bf16x8*)&As[aRow + mt * 16 * 64 + co];
#pragma unroll
      for (int nt = 0; nt < 4; ++nt)
        bfr[nt] = *(const bf16x8*)&Bs[bRow + nt * 16 * 64 + co];
#pragma unroll
      for (int mt = 0; mt < 4; ++mt)
#pragma unroll
        for (int nt = 0; nt < 4; ++nt)
          acc[mt][nt] = __builtin_amdgcn_mfma_f32_16x16x32_bf16(
              af[mt], bfr[nt], acc[mt][nt], 0, 0, 0);
    }
    __syncthreads();
  }

  // epilogue: C/D layout col=lane&15, row=(lane>>4)*4+reg
  const int cl = lane & 15;
  const int rq = (lane >> 4) * 4;
  if constexpr (FUSED) {
    float* Cf = (float*)Cv + (size_t)bz * (size_t)sC;
#pragma unroll
    for (int mt = 0; mt < 4; ++mt) {
      const int rbase = wm * 64 + mt * 16 + rq;
#pragma unroll
      for (int nt = 0; nt < 4; ++nt) {
        const int c = n0 + wn * 64 + nt * 16 + cl;
        const float cb = colBias[(size_t)bz * N + c];
#pragma unroll
        for (int r = 0; r < 4; ++r) {
          const int gr = m0 + rbase + r;
          Cf[(size_t)gr * N + c] =
              acc[mt][nt][r] + rowBias[(size_t)bz * M + gr] + cb;
        }
      }
    }
  } else {
    unsigned short* Cu = (unsigned short*)Cv;
#pragma unroll
    for (int mt = 0; mt < 4; ++mt) {
      const int rbase = wm * 64 + mt * 16 + rq;
#pragma unroll
      for (int nt = 0; nt < 4; ++nt) {
        const int c = n0 + wn * 64 + nt * 16 + cl;
#pragma unroll
        for (int r = 0; r < 4; ++r) {
          const int gr = m0 + rbase + r;
          Cu[(size_t)gr * N + c] = f32_to_bf16_rne(acc[mt][nt][r]);
        }
      }
    }
  }
}

// ---------- launch ----------
extern "C" void kernel_launch(void* const* d_in, const int* in_sizes, int n_in,
                              void* d_out, int out_size, void* d_ws,
                              size_t ws_size, hipStream_t stream) {
  const float* D = (const float*)d_in[0];  // (64,512,1024)
  const float* H = (const float*)d_in[1];  // (64,512,1024)
  const float* U = (const float*)d_in[2];  // (1024,1025)
  const float* W = (const float*)d_in[3];  // (2049,)
  float* out = (float*)d_out;              // (64,512,512)

  char* ws = (char*)d_ws;
  const size_t SZ = (size_t)32768 * 1024 * 2;  // 64 MiB per bf16 matrix
  unsigned short* Db = (unsigned short*)(ws);
  unsigned short* Hb = (unsigned short*)(ws + SZ);
  unsigned short* DU = (unsigned short*)(ws + 2 * SZ);
  unsigned short* Ut = (unsigned short*)(ws + 3 * SZ);
  float* cvec = (float*)(ws + 3 * SZ + (size_t)1024 * 1024 * 2);
  float* tvec = cvec + 32768;
  float* Ucol = tvec + 32768;

  prep_Ucol<<<dim3(4), dim3(256), 0, stream>>>(U, Ucol);
  prep_U<<<dim3(32, 32), dim3(256), 0, stream>>>(U, Ut);
  prep_rows<<<dim3(2048), dim3(256), 0, stream>>>(D, H, Ucol, W, Db, Hb, cvec,
                                                  tvec);

  // GEMM1: DU[r][j] = sum_i D[r][i] * U[i][j]   (M=32768, N=1024, K=1024)
  gemm_bt<false><<<dim3(8, 256, 1), dim3(256), 0, stream>>>(
      Db, Ut, (void*)DU, nullptr, nullptr, 32768, 1024, 1024, 0, 0, 0);

  // GEMM2: out[b][x][y] = sum_j DU[b,x,j]*H[b,y,j] + c[b,x] + t[b,y]
  gemm_bt<true><<<dim3(4, 4, 64), dim3(256), 0, stream>>>(
      DU, Hb, (void*)out, cvec, tvec, 512, 512, 1024,
      (long)512 * 1024, (long)512 * 1024, (long)512 * 512);
}